// Round 14
// baseline (358.990 us; speedup 1.0000x reference)
//
#include <hip/hip_runtime.h>

typedef unsigned long long ull;

#define NANCH    131072
#define NMAX     64
#define NBATCH   16
#define THREADS  256
#define APT      4                       // count role: anchors per thread
#define ACH      (THREADS*APT)           // 1024 anchors per count block
#define NCHUNK   (NANCH/ACH)             // 128
#define NB_CNT   (NCHUNK*NBATCH)         // 2048 count blocks (per-batch, fine)
#define AC_ANCH  256                     // argmax role: anchors per wave-chunk
#define BPB_A    128                     // blocks per bundle (4 waves each)
#define MAXB     16
#define NB_ARG   (MAXB*BPB_A)            // 2048 argmax blocks
#define GRID_MAIN (NB_CNT+NB_ARG)        // 4096, even=count odd=argmax

// ---------------------------------------------------------------------------
// ws layout (bytes):
//   0      : ull cells[1024]       per-(batch,gt) packed argmax
//   8192   : int done              completion counter (memset to 0 each call)
//   8256   : int lanepk[16*64]     bundle lane -> (batch<<8)|gt, -1 invalid
//   12352  : int nbund
//   12416  : double partials[2048] count-block sums (all rewritten each call)
// cells packed as (r_bits<<32)|(0x7FFFFFFF-idx), r = inter/(areaA+areaB) --
// monotone bijection of iou, >= 0, so float bits are unsigned-monotonic;
// ties -> larger low word -> smaller anchor index == JAX argmax
// first-occurrence semantics. cells memset to 0 (< any real pack).
// ---------------------------------------------------------------------------

__device__ __forceinline__ float focal_f(float p) {
    float om = 1.0f - p;
    return -om * om * __logf(p);
}

__global__ __launch_bounds__(64) void k_setup(
    const int* __restrict__ nobj, int* __restrict__ lanepk, int* __restrict__ nbund)
{
    int tid = threadIdx.x;
    for (int i = tid; i < MAXB*NMAX; i += 64) lanepk[i] = -1;
    __shared__ int s_b[NBATCH], s_no[NBATCH], s_bu[NBATCH], s_st[NBATCH];
    if (tid == 0) {
        int ord[NBATCH], key[NBATCH];
        for (int i = 0; i < NBATCH; ++i) { ord[i] = i; key[i] = nobj[i]; }
        for (int i = 1; i < NBATCH; ++i) {           // stable desc sort
            int k = key[i], o = ord[i], j = i-1;
            while (j >= 0 && key[j] < k) { key[j+1]=key[j]; ord[j+1]=ord[j]; --j; }
            key[j+1] = k; ord[j+1] = o;
        }
        int rem[MAXB]; int nb = 0;                   // FFD into 64-lane bundles
        for (int i = 0; i < NBATCH; ++i) {
            int n = key[i], f = -1;
            for (int x = 0; x < nb; ++x) if (rem[x] >= n) { f = x; break; }
            if (f < 0) { f = nb++; rem[f] = NMAX; }
            s_b[i] = ord[i]; s_no[i] = n; s_bu[i] = f; s_st[i] = NMAX - rem[f];
            rem[f] -= n;
        }
        *nbund = nb;
    }
    __syncthreads();
    #pragma unroll
    for (int i = 0; i < NBATCH; ++i)                 // cooperative lanepk fill
        if (tid < s_no[i])
            lanepk[s_bu[i]*NMAX + s_st[i] + tid] = (s_b[i] << 8) | tid;
}

// even bid -> count role (per-batch: finer blocks, smoother drain)
// odd  bid -> argmax role (R13-proven: 8 chains, reg double-buffer)
// LAST finishing block runs the correction + final reduction in-kernel.
__global__ __launch_bounds__(THREADS) void k_main(
    const float* __restrict__ thr_p,
    const float* __restrict__ classes,   // [B,A,2]
    const float* __restrict__ anchors,   // [A,4] xyxy
    const float* __restrict__ gt,        // [B,NMAX,4] xywh
    const int*   __restrict__ nobj,
    const int*   __restrict__ lanepk,
    const int*   __restrict__ nbund,
    ull* __restrict__ cells,
    double* __restrict__ partials,
    int* __restrict__ done,
    float* __restrict__ out)
{
    __shared__ float4 sbox[2*NMAX];      // count: first 64; tail: 128 (2 batches)
    __shared__ float  sqg[2*NMAX];
    __shared__ int    sidx2[2*NMAX];
    __shared__ int    snob[2];
    __shared__ double sw[4];
    __shared__ int    s_last;

    int bid = blockIdx.x, tid = threadIdx.x;
    int wv = tid >> 6, ln = tid & 63;
    float thr = *thr_p;
    float q   = thr / (1.0f + thr);      // iou>thr <=> inter > q*aarea + q*garea

    if ((bid & 1) == 0) {
        // ==================== count + focal role (one batch) ====================
        int cbid  = bid >> 1;            // 0..2047
        int chunk = cbid >> 4, b = cbid & 15;
        int no = nobj[b];
        if (tid < NMAX) {
            float4 g = reinterpret_cast<const float4*>(gt)[b*NMAX + tid];
            float x2 = g.x + g.z, y2 = g.y + g.w;
            float4 box = make_float4(g.x, g.y, x2, y2);
            float  qg  = q * ((x2 - g.x) * (y2 - g.y));
            if (tid >= no) { box = make_float4(4.f,4.f,4.f,4.f); qg = __builtin_inff(); }
            sbox[tid] = box; sqg[tid] = qg;
        }
        __syncthreads();

        float ax1[APT], ay1[APT], ax2[APT], ay2[APT], qa[APT];
        int abase = chunk * ACH + tid;
        #pragma unroll
        for (int k = 0; k < APT; ++k) {
            float4 v = reinterpret_cast<const float4*>(anchors)[abase + k*THREADS];
            ax1[k]=v.x; ay1[k]=v.y; ax2[k]=v.z; ay2[k]=v.w;
            qa[k] = q * ((v.z - v.x) * (v.w - v.y));
        }

        int no4 = (no + 3) & ~3;
        int cnt[APT];
        #pragma unroll
        for (int k = 0; k < APT; ++k) cnt[k] = 0;
        for (int n = 0; n < no4; n += 4) {
            #pragma unroll
            for (int u = 0; u < 4; ++u) {
                float4 g  = sbox[n + u];
                float  qg = sqg[n + u];
                #pragma unroll
                for (int k = 0; k < APT; ++k) {
                    float lx = fmaxf(ax1[k], g.x);
                    float ly = fmaxf(ay1[k], g.y);
                    float rx = fminf(ax2[k], g.z);
                    float ry = fminf(ay2[k], g.w);
                    float w  = fmaxf(rx - lx, 0.f);
                    float h  = fmaxf(ry - ly, 0.f);
                    float inter = w * h;
                    cnt[k] += (inter > qa[k] + qg) ? 1 : 0;
                }
            }
        }
        double acc = 0.0;
        const float2* cp = reinterpret_cast<const float2*>(classes) + (size_t)b * NANCH;
        #pragma unroll
        for (int k = 0; k < APT; ++k) {
            float2 c = cp[abase + k*THREADS];
            float p  = (cnt[k] > 0) ? c.y : c.x;
            acc += (double)(focal_f(p) * (1.0f + 10.0f * (float)cnt[k]));
        }
        #pragma unroll
        for (int off = 32; off; off >>= 1) acc += __shfl_xor(acc, off, 64);
        if (ln == 0) sw[wv] = acc;
        __syncthreads();
        if (tid == 0) partials[cbid] = sw[0] + sw[1] + sw[2] + sw[3];

    } else {
        // ==================== argmax role ====================
        int abid = bid >> 1;             // 0..2047
        int bu   = abid >> 7;
        int blkc = abid & (BPB_A - 1);
        if (bu < *nbund) {
            int abase = (blkc*4 + wv) * AC_ANCH;
            int lp = lanepk[bu*NMAX + ln];
            bool valid = lp >= 0;
            int gidx = valid ? ((lp >> 8)*NMAX + (lp & 255)) : 0;
            float4 gg = reinterpret_cast<const float4*>(gt)[gidx];
            float gx2 = gg.x + gg.z, gy2 = gg.y + gg.w;
            float gar = (gx2 - gg.x) * (gy2 - gg.y);

            float bn[8], bs[8]; int bj[8];
            #pragma unroll
            for (int u = 0; u < 8; ++u) { bn[u] = -1.f; bs[u] = 1.f; bj[u] = 0; }
            const float4* ap = reinterpret_cast<const float4*>(anchors) + abase;

            float4 va[4], vb[4];
            #pragma unroll
            for (int u = 0; u < 4; ++u) va[u] = ap[u];
            #pragma unroll
            for (int u = 0; u < 4; ++u) vb[u] = ap[4 + u];
            for (int j = 0; j < AC_ANCH; j += 8) {
                int jn = (j + 8 < AC_ANCH) ? (j + 8) : j;
                #pragma unroll
                for (int u = 0; u < 4; ++u) {
                    float4 v = va[u];
                    float aar = (v.z - v.x) * (v.w - v.y);
                    float lx = fmaxf(v.x, gg.x), ly = fmaxf(v.y, gg.y);
                    float rx = fminf(v.z, gx2),  ry = fminf(v.w, gy2);
                    float w  = fmaxf(rx - lx, 0.f), h = fmaxf(ry - ly, 0.f);
                    float inter = w * h;
                    float sa    = aar + gar;            // > 0
                    bool better = inter * bs[u] > bn[u] * sa;
                    bn[u] = better ? inter : bn[u];
                    bs[u] = better ? sa    : bs[u];
                    bj[u] = better ? (j+u) : bj[u];
                }
                #pragma unroll
                for (int u = 0; u < 4; ++u) va[u] = ap[jn + u];
                #pragma unroll
                for (int u = 0; u < 4; ++u) {
                    float4 v = vb[u];
                    float aar = (v.z - v.x) * (v.w - v.y);
                    float lx = fmaxf(v.x, gg.x), ly = fmaxf(v.y, gg.y);
                    float rx = fminf(v.z, gx2),  ry = fminf(v.w, gy2);
                    float w  = fmaxf(rx - lx, 0.f), h = fmaxf(ry - ly, 0.f);
                    float inter = w * h;
                    float sa    = aar + gar;
                    int c = 4 + u;
                    bool better = inter * bs[c] > bn[c] * sa;
                    bn[c] = better ? inter   : bn[c];
                    bs[c] = better ? sa      : bs[c];
                    bj[c] = better ? (j+4+u) : bj[c];
                }
                #pragma unroll
                for (int u = 0; u < 4; ++u) vb[u] = ap[jn + 4 + u];
            }
            if (valid) {
                ull best = 0;
                #pragma unroll
                for (int u = 0; u < 8; ++u) {
                    float rr = bn[u] * __builtin_amdgcn_rcpf(bs[u]);  // order only
                    unsigned aidx = (unsigned)(abase + bj[u]);
                    ull pk = ((ull)__float_as_uint(rr) << 32)
                           | (ull)(0x7FFFFFFFu - aidx);
                    best = pk > best ? pk : best;
                }
                atomicMax(&cells[(lp >> 8)*NMAX + (lp & 255)], best);
            }
        }
    }

    // ==================== completion + in-kernel tail ====================
    __threadfence();
    if (tid == 0) {
        int old = atomicAdd(done, 1);
        s_last = (old == GRID_MAIN - 1) ? 1 : 0;
    }
    __syncthreads();
    if (!s_last) return;
    __threadfence();                      // acquire: others' writes visible

    // -------- sparse forced-positive correction: 8 passes x 2 batches --------
    double dacc = 0.0;
    for (int pb = 0; pb < 8; ++pb) {
        if (tid < 2*NMAX) {
            int h = tid >> 6, n = tid & 63;
            int b = 2*pb + h;
            float4 g = reinterpret_cast<const float4*>(gt)[b*NMAX + n];
            float x2 = g.x + g.z, y2 = g.y + g.w;
            sbox[tid] = make_float4(g.x, g.y, x2, y2);
            sqg[tid]  = q * ((x2 - g.x) * (y2 - g.y));
            if (n == 0) snob[h] = nobj[b];
        }
        __syncthreads();

        int bi = -1; bool need = false;
        float4 av = make_float4(0.f,0.f,0.f,0.f);
        float qa = 0.f;
        int h = tid >> 6, n = tid & 63, b = 2*pb + h;
        if (tid < 2*NMAX && n < snob[h]) {
            ull pkv = cells[b*NMAX + n];
            bi = (int)(0x7FFFFFFFu - (unsigned)(pkv & 0xFFFFFFFFull));
            av = reinterpret_cast<const float4*>(anchors)[bi];
            float aar = (av.z - av.x) * (av.w - av.y);
            qa = q * aar;
            float4 g = sbox[tid];
            float lx = fmaxf(av.x, g.x), ly = fmaxf(av.y, g.y);
            float rx = fminf(av.z, g.z), ry = fminf(av.w, g.w);
            float w  = fmaxf(rx - lx, 0.f), hh = fmaxf(ry - ly, 0.f);
            float inter = w * hh;
            need = !(inter > qa + sqg[tid]);   // forced adds a bit only if !pos
        }
        if (tid < 2*NMAX) sidx2[tid] = need ? bi : -1;
        __syncthreads();

        if (need) {
            bool first = true; int extra = 0;
            int base = h * NMAX;
            for (int m = 0; m < NMAX; ++m) {
                if (sidx2[base + m] == bi) { if (m < n) first = false; ++extra; }
            }
            if (first) {
                int no = snob[h];
                int count = 0;
                for (int m = 0; m < no; ++m) {
                    float4 g = sbox[base + m];
                    float lx = fmaxf(av.x, g.x), ly = fmaxf(av.y, g.y);
                    float rx = fminf(av.z, g.z), ry = fminf(av.w, g.w);
                    float w  = fmaxf(rx - lx, 0.f), hh = fmaxf(ry - ly, 0.f);
                    float inter = w * hh;
                    count += (inter > qa + sqg[base + m]) ? 1 : 0;
                }
                float2 c = reinterpret_cast<const float2*>(classes)[(size_t)b * NANCH + bi];
                float po = (count > 0) ? c.y : c.x;
                float oldc = focal_f(po) * (1.0f + 10.0f * (float)count);
                int cn = count + extra;
                float pn = (cn > 0) ? c.y : c.x;
                float newc = focal_f(pn) * (1.0f + 10.0f * (float)cn);
                dacc += (double)newc - (double)oldc;
            }
        }
        __syncthreads();                  // protect sbox reuse next pass
    }

    // -------- final reduction: 2048 partials + deltas --------
    double v = dacc;
    #pragma unroll
    for (int k = 0; k < 8; ++k) v += partials[tid + k*256];
    #pragma unroll
    for (int off = 32; off; off >>= 1) v += __shfl_xor(v, off, 64);
    if (ln == 0) sw[wv] = v;
    __syncthreads();
    if (tid == 0) {
        double cls = (sw[0] + sw[1] + sw[2] + sw[3]) * (0.01 / 16.0);
        out[0] = (float)cls;              // total = class + coord(0)
        out[1] = (float)cls;
        out[2] = 0.0f;
    }
}

extern "C" void kernel_launch(void* const* d_in, const int* in_sizes, int n_in,
                              void* d_out, int out_size, void* d_ws, size_t ws_size,
                              hipStream_t stream) {
    const float* thr     = (const float*)d_in[0];
    const float* classes = (const float*)d_in[1];
    const float* anchors = (const float*)d_in[2];
    const float* gt      = (const float*)d_in[3];
    const int*   nobj    = (const int*)d_in[4];
    float* out = (float*)d_out;

    char* ws = (char*)d_ws;
    ull*    cells    = (ull*)(ws + 0);
    int*    done     = (int*)(ws + 8192);
    int*    lanepk   = (int*)(ws + 8256);
    int*    nbund    = (int*)(ws + 12352);
    double* partials = (double*)(ws + 12416);

    hipMemsetAsync(ws, 0, 8256, stream);             // cells + done
    k_setup<<<1, 64, 0, stream>>>(nobj, lanepk, nbund);
    k_main<<<GRID_MAIN, THREADS, 0, stream>>>(thr, classes, anchors, gt, nobj,
                                              lanepk, nbund, cells, partials,
                                              done, out);
}